// Round 4
// baseline (1283.269 us; speedup 1.0000x reference)
//
#include <hip/hip_runtime.h>

// Transformer layer, bf16 MFMA compute, fp32 I/O.
// B=2 T=2048 E=2048 H=16 DH=128 FFN=8192. Needs ~235MB workspace.

#define T_SEQ 2048
#define E_DIM 2048
#define N_HEAD 16
#define D_HEAD 128
#define FFN_DIM 8192
#define M_ROWS 4096  // B*T

typedef unsigned short u16;
typedef short short8 __attribute__((ext_vector_type(8)));
typedef float f32x4 __attribute__((ext_vector_type(4)));

#define DEV __device__ __forceinline__

DEV u16 f2bf(float f) {
  unsigned u = __float_as_uint(f);
  u += 0x7fffu + ((u >> 16) & 1u);
  return (u16)(u >> 16);
}
DEV float bf2f(u16 h) { return __uint_as_float(((unsigned)h) << 16); }

DEV void async16(void* lds, const void* g) {
  __builtin_amdgcn_global_load_lds((const __attribute__((address_space(1))) void*)g,
                                   (__attribute__((address_space(3))) void*)lds, 16, 0, 0);
}

// ---------------- LayerNorm: fp32 [rows][E] -> bf16 -----------------
__global__ __launch_bounds__(256) void ln_kernel(const float* __restrict__ x,
                                                 const float* __restrict__ gw,
                                                 const float* __restrict__ bw,
                                                 u16* __restrict__ out) {
  int row = blockIdx.x;
  int t = threadIdx.x;
  const float4* xr = (const float4*)(x + (size_t)row * E_DIM);
  float4 a = xr[t], c = xr[t + 256];
  float s = a.x + a.y + a.z + a.w + c.x + c.y + c.z + c.w;
  float q = a.x * a.x + a.y * a.y + a.z * a.z + a.w * a.w +
            c.x * c.x + c.y * c.y + c.z * c.z + c.w * c.w;
  for (int off = 32; off > 0; off >>= 1) {
    s += __shfl_down(s, off);
    q += __shfl_down(q, off);
  }
  __shared__ float red[8];
  if ((t & 63) == 0) { red[(t >> 6) * 2] = s; red[(t >> 6) * 2 + 1] = q; }
  __syncthreads();
  s = red[0] + red[2] + red[4] + red[6];
  q = red[1] + red[3] + red[5] + red[7];
  float mu = s * (1.f / E_DIM);
  float rs = rsqrtf(q * (1.f / E_DIM) - mu * mu + 1e-5f);
  const float4* g4 = (const float4*)gw;
  const float4* b4 = (const float4*)bw;
  float4 g0 = g4[t], g1v = g4[t + 256], e0 = b4[t], e1 = b4[t + 256];
  ushort4 o0, o1;
  o0.x = f2bf((a.x - mu) * rs * g0.x + e0.x);
  o0.y = f2bf((a.y - mu) * rs * g0.y + e0.y);
  o0.z = f2bf((a.z - mu) * rs * g0.z + e0.z);
  o0.w = f2bf((a.w - mu) * rs * g0.w + e0.w);
  o1.x = f2bf((c.x - mu) * rs * g1v.x + e1.x);
  o1.y = f2bf((c.y - mu) * rs * g1v.y + e1.y);
  o1.z = f2bf((c.z - mu) * rs * g1v.z + e1.z);
  o1.w = f2bf((c.w - mu) * rs * g1v.w + e1.w);
  ((ushort4*)(out + (size_t)row * E_DIM))[t] = o0;
  ((ushort4*)(out + (size_t)row * E_DIM))[t + 256] = o1;
}

// ------- convert+transpose: fp32 W[K][N] -> bf16 WT[N][K] -----------
__global__ __launch_bounds__(256) void cvt_t_kernel(const float* __restrict__ W,
                                                    u16* __restrict__ WT,
                                                    int Kd, int Nd) {
  __shared__ float tile[32][33];
  int tx = threadIdx.x, ty = threadIdx.y;
  int n0 = blockIdx.x * 32, k0 = blockIdx.y * 32;
#pragma unroll
  for (int i = 0; i < 4; i++)
    tile[ty + i * 8][tx] = W[(size_t)(k0 + ty + i * 8) * Nd + n0 + tx];
  __syncthreads();
#pragma unroll
  for (int i = 0; i < 4; i++)
    WT[(size_t)(n0 + ty + i * 8) * Kd + k0 + tx] = f2bf(tile[tx][ty + i * 8]);
}

// ------- transpose V per batch: bf16 [B*T][E] -> [B][E][T] ----------
__global__ __launch_bounds__(256) void transpose_v_kernel(const u16* __restrict__ v,
                                                          u16* __restrict__ vt) {
  __shared__ u16 tile[32][33];
  int tx = threadIdx.x, ty = threadIdx.y;
  int b = blockIdx.z;
  int t0 = blockIdx.x * 32, e0 = blockIdx.y * 32;
#pragma unroll
  for (int i = 0; i < 4; i++)
    tile[ty + i * 8][tx] = v[(size_t)(b * T_SEQ + t0 + ty + i * 8) * E_DIM + e0 + tx];
  __syncthreads();
#pragma unroll
  for (int i = 0; i < 4; i++)
    vt[((size_t)b * E_DIM + e0 + ty + i * 8) * T_SEQ + t0 + tx] = tile[tx][ty + i * 8];
}

// ====== GEMM 128xBNxBK64, 512 thr (8 waves), TRI-buffered LDS =======
// C[M][N] = A[M][K] * BT[N][K]^T.
// Tri-buffer removes the write-after-read hazard entirely: staging
// tile kt+2 targets a buffer with no live readers, so the K-loop has
// ONE barrier + one counted vmcnt per tile, no lgkmcnt drains, and
// loads stay in flight across barriers (T4). T2 swizzle (row&7)^chunk
// on pre-swizzled global src + swizzled ds_read (proven 0-conflict).
// T5 setprio around the MFMA cluster. T1 bijective XCD swizzle.
// MODE 0: bf16 C.  MODE 1: Cout(f32) = Extra(f32) + acc.
// MODE 2: Cout(bf16) = silu(Extra bf16) * acc (Extra may alias Cout).
template <int MODE, int BN>
__global__ __launch_bounds__(512, 1) void gemm_tri(const u16* __restrict__ A,
                                                   const u16* __restrict__ BT,
                                                   void* Cout, const void* Extra,
                                                   int N, int K, int colMajorXcd) {
  constexpr int WN = BN / 64;        // waves along N (4 or 2)
  constexpr int WM = 8 / WN;         // waves along M (2 or 4)
  constexpr int WR = 128 / WM;       // rows per wave (64 or 32)
  constexpr int MREP = WR / 16;      // row fragments (4 or 2)
  constexpr int RT = 2 + BN / 64;    // async16 rounds per tile (6 or 4)
  constexpr int ASZ = 128 * 64;      // elems per A buffer
  constexpr int BSZ = BN * 64;       // elems per B buffer

  __shared__ u16 As[3 * ASZ];
  __shared__ u16 Bs[3 * BSZ];
  const int t = threadIdx.x;
  const int w = t >> 6, l = t & 63;
  const int g = l >> 4, lq = l & 15;
  const int wm = w / WN, wn = w % WN;

  // ---- bijective XCD swizzle (nwg % 8 == 0 for all our shapes) ----
  const int gx = gridDim.x, gy = gridDim.y;
  const int nwg = gx * gy;
  int lin = colMajorXcd ? (blockIdx.x * gy + blockIdx.y)
                        : (blockIdx.y * gx + blockIdx.x);
  const int q = nwg >> 3;
  int wg = (lin & 7) * q + (lin >> 3);
  int bx, by;
  if (colMajorXcd) { bx = wg / gy; by = wg - bx * gy; }
  else             { by = wg / gx; bx = wg - by * gx; }
  const size_t bm = (size_t)by * 128, bn = (size_t)bx * BN;

  // ---- staging addresses (pre-swizzled global source, rule #21) ----
  const int srow = l >> 3;                     // 0..7
  const int schunk = ((l & 7) ^ srow) << 3;    // swizzled elem offset in row
  const u16* Asrc = A + (bm + 8 * w + srow) * (size_t)K + schunk;
  const u16* Bsrc = BT + (bn + 8 * w + srow) * (size_t)K + schunk;

#define STAGE_TILE(SC, KT)                                              \
  {                                                                     \
    u16* Ad = As + (SC) * ASZ + w * 512;                                \
    u16* Bd = Bs + (SC) * BSZ + w * 512;                                \
    size_t ko = (size_t)(KT) * 64;                                      \
    async16(Ad, Asrc + ko);                                             \
    async16(Ad + 4096, Asrc + (size_t)64 * K + ko);                     \
    async16(Bd, Bsrc + ko);                                             \
    async16(Bd + 4096, Bsrc + (size_t)64 * K + ko);                     \
    if constexpr (BN == 256) {                                          \
      async16(Bd + 8192, Bsrc + (size_t)128 * K + ko);                  \
      async16(Bd + 12288, Bsrc + (size_t)192 * K + ko);                 \
    }                                                                   \
  }

  const int NT = K >> 6;
  STAGE_TILE(0, 0);
  STAGE_TILE(1, 1);

  f32x4 acc[MREP][4] = {};

  int bc = 0;
  for (int kt = 0; kt < NT; ++kt) {
    if (kt < NT - 1) {
      if constexpr (BN == 256) asm volatile("s_waitcnt vmcnt(6)" ::: "memory");
      else                     asm volatile("s_waitcnt vmcnt(4)" ::: "memory");
    } else {
      asm volatile("s_waitcnt vmcnt(0)" ::: "memory");
    }
    asm volatile("s_barrier" ::: "memory");
    if (kt + 2 < NT) {
      int sc = bc - 1; if (sc < 0) sc = 2;   // (bc+2)%3
      STAGE_TILE(sc, kt + 2);
    }
    const u16* Ab = As + bc * ASZ;
    const u16* Bb = Bs + bc * BSZ;
    short8 af[2][MREP], bf[2][4];
#pragma unroll
    for (int ks = 0; ks < 2; ks++) {
#pragma unroll
      for (int m = 0; m < MREP; m++)
        af[ks][m] = *(const short8*)(Ab + (wm * WR + m * 16 + lq) * 64 +
                                     (((ks * 4 + g) ^ (lq & 7)) << 3));
#pragma unroll
      for (int n = 0; n < 4; n++)
        bf[ks][n] = *(const short8*)(Bb + (wn * 64 + n * 16 + lq) * 64 +
                                     (((ks * 4 + g) ^ (lq & 7)) << 3));
    }
    __builtin_amdgcn_s_setprio(1);
#pragma unroll
    for (int ks = 0; ks < 2; ks++)
#pragma unroll
      for (int m = 0; m < MREP; m++)
#pragma unroll
        for (int n = 0; n < 4; n++)
          acc[m][n] = __builtin_amdgcn_mfma_f32_16x16x32_bf16(af[ks][m], bf[ks][n],
                                                              acc[m][n], 0, 0, 0);
    __builtin_amdgcn_s_setprio(0);
    bc = (bc == 2) ? 0 : bc + 1;
  }
#undef STAGE_TILE

#pragma unroll
  for (int m = 0; m < MREP; m++) {
    size_t row = bm + wm * WR + m * 16 + 4 * g;
#pragma unroll
    for (int n = 0; n < 4; n++) {
      size_t col = bn + wn * 64 + n * 16 + lq;
#pragma unroll
      for (int r = 0; r < 4; r++) {
        size_t idx = (row + r) * (size_t)N + col;
        if constexpr (MODE == 0) {
          ((u16*)Cout)[idx] = f2bf(acc[m][n][r]);
        } else if constexpr (MODE == 1) {
          ((float*)Cout)[idx] = ((const float*)Extra)[idx] + acc[m][n][r];
        } else {
          float a = bf2f(((const u16*)Extra)[idx]);
          float sil = a / (1.f + exp2f(-1.4426950408889634f * a));
          ((u16*)Cout)[idx] = f2bf(sil * acc[m][n][r]);
        }
      }
    }
  }
}

// ----------------- causal flash attention (LDS-staged) --------------
// grid (T/64, B*H); 4 waves/block; block owns 64 q-rows of one (b,h);
// wave w owns rows q0blk + 16w .. +16.  KV tile = 64.
__global__ __launch_bounds__(256, 3) void attn_kernel(const u16* __restrict__ Q,
                                                      const u16* __restrict__ Kb,
                                                      const u16* __restrict__ VT,
                                                      u16* __restrict__ CTX) {
  __shared__ u16 Ks[64 * 128];    // 16 KB
  __shared__ u16 Vs[128 * 64];    // 16 KB
  __shared__ u16 P_all[4][16 * 72];  // 9 KB, per-wave padded P tile
  const int t = threadIdx.x;
  const int w = t >> 6, l = t & 63, g = l >> 4, lq = l & 15;
  u16* P = P_all[w];
  const int q0blk = blockIdx.x * 64;
  const int q0w = q0blk + w * 16;
  const int bh = blockIdx.y, b = bh >> 4, h = bh & 15;
  const u16* qp = Q + (size_t)b * T_SEQ * E_DIM + h * D_HEAD;
  const u16* kp = Kb + (size_t)b * T_SEQ * E_DIM + h * D_HEAD;
  const u16* vp = VT + ((size_t)b * E_DIM + h * D_HEAD) * T_SEQ;

  short8 qf[4];
#pragma unroll
  for (int ks = 0; ks < 4; ks++)
    qf[ks] = *(const short8*)(qp + (size_t)(q0w + lq) * E_DIM + ks * 32 + g * 8);

  f32x4 acc[8] = {};
  float m2[4], ls[4];
#pragma unroll
  for (int r = 0; r < 4; r++) { m2[r] = -1e30f; ls[r] = 0.f; }
  const float sc = 0.08838834764831845f * 1.4426950408889634f;  // 1/sqrt(128)*log2e

  const int kRow0 = 16 * w + (l >> 4);
  const int kChunk = l & 15;
  const int vRow0 = 32 * w + (l >> 3);
  const int vChunk = l & 7;

  for (int kv0 = 0; kv0 <= q0blk; kv0 += 64) {
#pragma unroll
    for (int j = 0; j < 4; j++) {
      int R = kRow0 + 4 * j;
      async16(Ks + (16 * w + 4 * j) * 128,
              kp + (size_t)(kv0 + R) * E_DIM + ((kChunk ^ (R & 7)) << 3));
    }
#pragma unroll
    for (int j = 0; j < 4; j++) {
      int D = vRow0 + 8 * j;
      async16(Vs + (32 * w + 8 * j) * 64,
              vp + (size_t)D * T_SEQ + kv0 + ((vChunk ^ (D & 7)) << 3));
    }
    __syncthreads();

    f32x4 s[4];
#pragma unroll
    for (int ct = 0; ct < 4; ct++) {
      s[ct] = f32x4{0.f, 0.f, 0.f, 0.f};
#pragma unroll
      for (int ks = 0; ks < 4; ks++) {
        short8 kf = *(const short8*)(Ks + (ct * 16 + lq) * 128 +
                                     (((ks * 4 + g) ^ (lq & 7)) << 3));
        s[ct] = __builtin_amdgcn_mfma_f32_16x16x32_bf16(qf[ks], kf, s[ct], 0, 0, 0);
      }
    }
    float sv[4][4];
#pragma unroll
    for (int ct = 0; ct < 4; ct++)
#pragma unroll
      for (int r = 0; r < 4; r++) sv[ct][r] = s[ct][r] * sc;
    if (kv0 + 64 > q0w) {
#pragma unroll
      for (int ct = 0; ct < 4; ct++)
#pragma unroll
        for (int r = 0; r < 4; r++)
          if (kv0 + ct * 16 + lq > q0w + 4 * g + r) sv[ct][r] = -1e30f;
    }
    float mx[4];
#pragma unroll
    for (int r = 0; r < 4; r++)
      mx[r] = fmaxf(fmaxf(sv[0][r], sv[1][r]), fmaxf(sv[2][r], sv[3][r]));
#pragma unroll
    for (int off = 1; off < 16; off <<= 1)
#pragma unroll
      for (int r = 0; r < 4; r++) mx[r] = fmaxf(mx[r], __shfl_xor(mx[r], off));
#pragma unroll
    for (int r = 0; r < 4; r++) {
      float mn = fmaxf(m2[r], mx[r]);
      float sca = exp2f(m2[r] - mn);
      m2[r] = mn;
      float sum = 0.f;
#pragma unroll
      for (int ct = 0; ct < 4; ct++) {
        float pv = exp2f(sv[ct][r] - mn);
        sum += pv;
        P[(4 * g + r) * 72 + ct * 16 + lq] = f2bf(pv);
      }
      ls[r] = ls[r] * sca + sum;
#pragma unroll
      for (int n = 0; n < 8; n++) acc[n][r] *= sca;
    }
    short8 pa[2];
#pragma unroll
    for (int ks2 = 0; ks2 < 2; ks2++)
      pa[ks2] = *(const short8*)(P + lq * 72 + ks2 * 32 + g * 8);
#pragma unroll
    for (int n = 0; n < 8; n++)
#pragma unroll
      for (int ks2 = 0; ks2 < 2; ks2++) {
        short8 vf = *(const short8*)(Vs + (n * 16 + lq) * 64 +
                                     (((ks2 * 4 + g) ^ (lq & 7)) << 3));
        acc[n] = __builtin_amdgcn_mfma_f32_16x16x32_bf16(pa[ks2], vf, acc[n], 0, 0, 0);
      }
    __syncthreads();
  }

#pragma unroll
  for (int off = 1; off < 16; off <<= 1)
#pragma unroll
    for (int r = 0; r < 4; r++) ls[r] += __shfl_xor(ls[r], off);
  float inv[4];
#pragma unroll
  for (int r = 0; r < 4; r++) inv[r] = 1.f / ls[r];
  u16* cp = CTX + ((size_t)b * T_SEQ + q0w) * E_DIM + h * D_HEAD;
#pragma unroll
  for (int n = 0; n < 8; n++)
#pragma unroll
    for (int r = 0; r < 4; r++)
      cp[(size_t)(4 * g + r) * E_DIM + n * 16 + lq] = f2bf(acc[n][r] * inv[r]);
}

extern "C" void kernel_launch(void* const* d_in, const int* in_sizes, int n_in,
                              void* d_out, int out_size, void* d_ws, size_t ws_size,
                              hipStream_t stream) {
  (void)in_sizes; (void)n_in; (void)out_size; (void)ws_size;
  const float* x  = (const float*)d_in[0];
  const float* g1 = (const float*)d_in[1];
  const float* b1 = (const float*)d_in[2];
  const float* wq = (const float*)d_in[3];
  const float* wk = (const float*)d_in[4];
  const float* wv = (const float*)d_in[5];
  const float* wo = (const float*)d_in[6];
  const float* g2 = (const float*)d_in[7];
  const float* b2 = (const float*)d_in[8];
  const float* w1 = (const float*)d_in[9];
  const float* w2 = (const float*)d_in[10];
  const float* w3 = (const float*)d_in[11];
  float* out = (float*)d_out;

  const size_t EE2 = (size_t)E_DIM * E_DIM * 2;
  const size_t EF2 = (size_t)E_DIM * FFN_DIM * 2;
  const size_t ME2 = (size_t)M_ROWS * E_DIM * 2;
  char* p = (char*)d_ws;
  u16* wqT = (u16*)p; p += EE2;
  u16* wkT = (u16*)p; p += EE2;
  u16* wvT = (u16*)p; p += EE2;
  u16* woT = (u16*)p; p += EE2;
  u16* w1T = (u16*)p; p += EF2;
  u16* w2T = (u16*)p; p += EF2;
  u16* w3T = (u16*)p; p += EF2;
  u16* Hb  = (u16*)p; p += ME2;
  u16* Qb  = (u16*)p; p += ME2;
  u16* Kbf = (u16*)p; p += ME2;
  u16* Vb  = (u16*)p; p += ME2;
  u16* VTb = (u16*)p; p += ME2;
  u16* CTXb = (u16*)p; p += ME2;
  u16* U1b = Qb;  // u1/gated (67MB) reuses dead q/k/v/vT region

  dim3 blk32(32, 8);
  // weights -> bf16 transposed [N][K]
  cvt_t_kernel<<<dim3(E_DIM / 32, E_DIM / 32), blk32, 0, stream>>>(wq, wqT, E_DIM, E_DIM);
  cvt_t_kernel<<<dim3(E_DIM / 32, E_DIM / 32), blk32, 0, stream>>>(wk, wkT, E_DIM, E_DIM);
  cvt_t_kernel<<<dim3(E_DIM / 32, E_DIM / 32), blk32, 0, stream>>>(wv, wvT, E_DIM, E_DIM);
  cvt_t_kernel<<<dim3(E_DIM / 32, E_DIM / 32), blk32, 0, stream>>>(wo, woT, E_DIM, E_DIM);
  cvt_t_kernel<<<dim3(FFN_DIM / 32, E_DIM / 32), blk32, 0, stream>>>(w1, w1T, E_DIM, FFN_DIM);
  cvt_t_kernel<<<dim3(FFN_DIM / 32, E_DIM / 32), blk32, 0, stream>>>(w2, w2T, E_DIM, FFN_DIM);
  cvt_t_kernel<<<dim3(E_DIM / 32, FFN_DIM / 32), blk32, 0, stream>>>(w3, w3T, FFN_DIM, E_DIM);

  // attention block
  ln_kernel<<<M_ROWS, 256, 0, stream>>>(x, g1, b1, Hb);
  gemm_tri<0, 128><<<dim3(E_DIM / 128, M_ROWS / 128), 512, 0, stream>>>(Hb, wqT, Qb, nullptr, E_DIM, E_DIM, 1);
  gemm_tri<0, 128><<<dim3(E_DIM / 128, M_ROWS / 128), 512, 0, stream>>>(Hb, wkT, Kbf, nullptr, E_DIM, E_DIM, 1);
  gemm_tri<0, 128><<<dim3(E_DIM / 128, M_ROWS / 128), 512, 0, stream>>>(Hb, wvT, Vb, nullptr, E_DIM, E_DIM, 1);
  transpose_v_kernel<<<dim3(T_SEQ / 32, E_DIM / 32, 2), blk32, 0, stream>>>(Vb, VTb);
  attn_kernel<<<dim3(T_SEQ / 64, 2 * N_HEAD), 256, 0, stream>>>(Qb, Kbf, VTb, CTXb);
  gemm_tri<1, 128><<<dim3(E_DIM / 128, M_ROWS / 128), 512, 0, stream>>>(CTXb, woT, out, x, E_DIM, E_DIM, 1);

  // SwiGLU MLP block
  ln_kernel<<<M_ROWS, 256, 0, stream>>>(out, g2, b2, Hb);
  gemm_tri<0, 256><<<dim3(FFN_DIM / 256, M_ROWS / 128), 512, 0, stream>>>(Hb, w1T, U1b, nullptr, FFN_DIM, E_DIM, 1);
  gemm_tri<2, 256><<<dim3(FFN_DIM / 256, M_ROWS / 128), 512, 0, stream>>>(Hb, w2T, U1b, U1b, FFN_DIM, E_DIM, 1);
  gemm_tri<1, 128><<<dim3(E_DIM / 128, M_ROWS / 128), 512, 0, stream>>>(U1b, w3T, out, out, E_DIM, FFN_DIM, 1);
}

// Round 5
// 1021.280 us; speedup vs baseline: 1.2565x; 1.2565x over previous
//
#include <hip/hip_runtime.h>

// Transformer layer, bf16 MFMA compute, fp32 I/O.
// B=2 T=2048 E=2048 H=16 DH=128 FFN=8192. Needs ~235MB workspace.

#define T_SEQ 2048
#define E_DIM 2048
#define N_HEAD 16
#define D_HEAD 128
#define FFN_DIM 8192
#define M_ROWS 4096  // B*T
#define QS (3 * E_DIM)  // fused QKV row stride

typedef unsigned short u16;
typedef short short8 __attribute__((ext_vector_type(8)));
typedef float f32x4 __attribute__((ext_vector_type(4)));

#define DEV __device__ __forceinline__

DEV u16 f2bf(float f) {
  unsigned u = __float_as_uint(f);
  u += 0x7fffu + ((u >> 16) & 1u);
  return (u16)(u >> 16);
}
DEV float bf2f(u16 h) { return __uint_as_float(((unsigned)h) << 16); }

DEV void async16(void* lds, const void* g) {
  __builtin_amdgcn_global_load_lds((const __attribute__((address_space(1))) void*)g,
                                   (__attribute__((address_space(3))) void*)lds, 16, 0, 0);
}

// ---------------- LayerNorm: fp32 [rows][E] -> bf16 -----------------
__global__ __launch_bounds__(256) void ln_kernel(const float* __restrict__ x,
                                                 const float* __restrict__ gw,
                                                 const float* __restrict__ bw,
                                                 u16* __restrict__ out) {
  int row = blockIdx.x;
  int t = threadIdx.x;
  const float4* xr = (const float4*)(x + (size_t)row * E_DIM);
  float4 a = xr[t], c = xr[t + 256];
  float s = a.x + a.y + a.z + a.w + c.x + c.y + c.z + c.w;
  float q = a.x * a.x + a.y * a.y + a.z * a.z + a.w * a.w +
            c.x * c.x + c.y * c.y + c.z * c.z + c.w * c.w;
  for (int off = 32; off > 0; off >>= 1) {
    s += __shfl_down(s, off);
    q += __shfl_down(q, off);
  }
  __shared__ float red[8];
  if ((t & 63) == 0) { red[(t >> 6) * 2] = s; red[(t >> 6) * 2 + 1] = q; }
  __syncthreads();
  s = red[0] + red[2] + red[4] + red[6];
  q = red[1] + red[3] + red[5] + red[7];
  float mu = s * (1.f / E_DIM);
  float rs = rsqrtf(q * (1.f / E_DIM) - mu * mu + 1e-5f);
  const float4* g4 = (const float4*)gw;
  const float4* b4 = (const float4*)bw;
  float4 g0 = g4[t], g1v = g4[t + 256], e0 = b4[t], e1 = b4[t + 256];
  ushort4 o0, o1;
  o0.x = f2bf((a.x - mu) * rs * g0.x + e0.x);
  o0.y = f2bf((a.y - mu) * rs * g0.y + e0.y);
  o0.z = f2bf((a.z - mu) * rs * g0.z + e0.z);
  o0.w = f2bf((a.w - mu) * rs * g0.w + e0.w);
  o1.x = f2bf((c.x - mu) * rs * g1v.x + e1.x);
  o1.y = f2bf((c.y - mu) * rs * g1v.y + e1.y);
  o1.z = f2bf((c.z - mu) * rs * g1v.z + e1.z);
  o1.w = f2bf((c.w - mu) * rs * g1v.w + e1.w);
  ((ushort4*)(out + (size_t)row * E_DIM))[t] = o0;
  ((ushort4*)(out + (size_t)row * E_DIM))[t + 256] = o1;
}

// ------- convert+transpose: fp32 W[K][N] -> bf16 WT[N][K] -----------
__global__ __launch_bounds__(256) void cvt_t_kernel(const float* __restrict__ W,
                                                    u16* __restrict__ WT,
                                                    int Kd, int Nd) {
  __shared__ float tile[32][33];
  int tx = threadIdx.x, ty = threadIdx.y;
  int n0 = blockIdx.x * 32, k0 = blockIdx.y * 32;
#pragma unroll
  for (int i = 0; i < 4; i++)
    tile[ty + i * 8][tx] = W[(size_t)(k0 + ty + i * 8) * Nd + n0 + tx];
  __syncthreads();
#pragma unroll
  for (int i = 0; i < 4; i++)
    WT[(size_t)(n0 + ty + i * 8) * Kd + k0 + tx] = f2bf(tile[tx][ty + i * 8]);
}

// -- transpose V from fused QKV: bf16 [B*T][QS] col 4096+ -> [B][E][T]
__global__ __launch_bounds__(256) void transpose_v_kernel(const u16* __restrict__ qkv,
                                                          u16* __restrict__ vt) {
  __shared__ u16 tile[32][33];
  int tx = threadIdx.x, ty = threadIdx.y;
  int b = blockIdx.z;
  int t0 = blockIdx.x * 32, e0 = blockIdx.y * 32;
#pragma unroll
  for (int i = 0; i < 4; i++)
    tile[ty + i * 8][tx] =
        qkv[(size_t)(b * T_SEQ + t0 + ty + i * 8) * QS + 2 * E_DIM + e0 + tx];
  __syncthreads();
#pragma unroll
  for (int i = 0; i < 4; i++)
    vt[((size_t)b * E_DIM + e0 + ty + i * 8) * T_SEQ + t0 + tx] = tile[tx][ty + i * 8];
}

// ========= GEMM 256x256xBK64, 8-phase schedule (m201 port) ==========
// C[M][N] = A[M][K] * BT[N][K]^T.  512 thr = 8 waves (2M x 4N), each
// wave owns 128x64.  LDS: A,B as [2 dbuf][2 K-half][256 rows][32 cols]
// (64KB each).  Phase = {ds_read subtile + stage one half (2 async16)}
// -> barrier -> lgkmcnt(0) -> setprio(1) 16 MFMA setprio(0) -> barrier.
// Staging stagger (iter j, tiles t1=2j+1,t2=2j+2,t3=2j+3):
//   p0:A[1][1]<-t1  p1:B[1][1]<-t1  p2:A[0][0]<-t2  p3:B[0][0]<-t2
//   p4:A[0][1]<-t2  p5:B[0][1]<-t2  p6:A[1][0]<-t3  p7:B[1][0]<-t3
// Every slot is restaged exactly >=1 phase after its last ds_read.
// Counted vmcnt(4) before the barriers ending p3 and p7 (T4): drains
// the next dbuf's 8 loads, leaves 4 in flight; 6-phase HBM lookahead.
// Swizzle: chunk ^= (row ^ row>>2)&3 on both stage-source and ds_read.
// MODE 0: bf16 C.  MODE 1: Cout(f32)=Extra(f32)+acc.
// MODE 2: Cout(bf16)=silu(Extra bf16)*acc (Extra may alias Cout).
template <int MODE>
__global__ __launch_bounds__(512, 1) void gemm8p(const u16* __restrict__ A,
                                                 const u16* __restrict__ BT,
                                                 void* __restrict__ Cout,
                                                 const void* __restrict__ Extra,
                                                 int N, int K, int colMajorXcd) {
  __shared__ u16 Abuf[2 * 2 * 256 * 32];  // 64 KB
  __shared__ u16 Bbuf[2 * 2 * 256 * 32];  // 64 KB
  const int t = threadIdx.x;
  const int w = t >> 6, l = t & 63, g = l >> 4, lq = l & 15;
  const int wm = w >> 2, wn = w & 3;

  // T1: bijective XCD swizzle (all grids have nwg % 8 == 0)
  const int gx = gridDim.x, gy = gridDim.y;
  const int nwg = gx * gy;
  int lin = colMajorXcd ? (blockIdx.x * gy + blockIdx.y)
                        : (blockIdx.y * gx + blockIdx.x);
  const int qq = nwg >> 3;
  int wg = (lin & 7) * qq + (lin >> 3);
  int bx, by;
  if (colMajorXcd) { bx = wg / gy; by = wg - bx * gy; }
  else             { by = wg / gx; bx = wg - by * gx; }
  const size_t bm = (size_t)by * 256, bn = (size_t)bx * 256;

  // staging lane decomposition: 16B per lane; 4 lanes/row, 16 rows/wave
  const int srow = l >> 2;
  const int sswz = (((l & 3) ^ ((srow ^ (srow >> 2)) & 3)) << 3);
  const int rdswz = ((g ^ ((lq ^ (lq >> 2)) & 3)) << 3);
  const u16* aS0 = A + (bm + w * 16 + srow) * (size_t)K + sswz;
  const u16* aS1 = A + (bm + 128 + w * 16 + srow) * (size_t)K + sswz;
  const u16* bS0 = BT + (bn + w * 16 + srow) * (size_t)K + sswz;
  const u16* bS1 = BT + (bn + 128 + w * 16 + srow) * (size_t)K + sswz;

#define STA8(DB, KS, TILE)                                                   \
  {                                                                          \
    size_t off_ = (size_t)(TILE) * 64 + (KS) * 32;                           \
    async16(Abuf + (DB) * 16384 + (KS) * 8192 + w * 512, aS0 + off_);        \
    async16(Abuf + (DB) * 16384 + (KS) * 8192 + 4096 + w * 512, aS1 + off_); \
  }
#define STB8(DB, KS, TILE)                                                   \
  {                                                                          \
    size_t off_ = (size_t)(TILE) * 64 + (KS) * 32;                           \
    async16(Bbuf + (DB) * 16384 + (KS) * 8192 + w * 512, bS0 + off_);        \
    async16(Bbuf + (DB) * 16384 + (KS) * 8192 + 4096 + w * 512, bS1 + off_); \
  }
#define RDA8(DB, KS, MH)                                                     \
  _Pragma("unroll") for (int mm = 0; mm < 4; ++mm)                           \
      af[mm] = *(const short8*)(Abuf + (DB) * 16384 + (KS) * 8192 +          \
                                (wm * 128 + (MH) * 64 + mm * 16 + lq) * 32 + \
                                rdswz);
#define RDB8(DB, KS)                                                         \
  _Pragma("unroll") for (int nn = 0; nn < 4; ++nn)                           \
      bf[nn] = *(const short8*)(Bbuf + (DB) * 16384 + (KS) * 8192 +          \
                                (wn * 64 + nn * 16 + lq) * 32 + rdswz);
#define MM168(MH)                                                            \
  _Pragma("unroll") for (int mm = 0; mm < 4; ++mm)                           \
      _Pragma("unroll") for (int nn = 0; nn < 4; ++nn)                       \
          acc[(MH) * 4 + mm][nn] = __builtin_amdgcn_mfma_f32_16x16x32_bf16(  \
              af[mm], bf[nn], acc[(MH) * 4 + mm][nn], 0, 0, 0);
#define SYNCA                                                                \
  asm volatile("s_barrier" ::: "memory");                                    \
  asm volatile("s_waitcnt lgkmcnt(0)" ::: "memory");                         \
  __builtin_amdgcn_sched_barrier(0);                                         \
  __builtin_amdgcn_s_setprio(1);
#define ENDP                                                                 \
  __builtin_amdgcn_s_setprio(0);
#define BAR2 asm volatile("s_barrier" ::: "memory");

  const int NT = K >> 6, NI = NT >> 1;
  f32x4 acc[8][4] = {};
  short8 af[4], bf[4];

  // prologue: tile0 both K-halves + tile1 K-half0  (12 loads/thread)
  STA8(0, 0, 0); STB8(0, 0, 0);
  STA8(0, 1, 0); STB8(0, 1, 0);
  STA8(1, 0, 1); STB8(1, 0, 1);
  asm volatile("s_waitcnt vmcnt(4)" ::: "memory");  // tile0 resident
  BAR2;

  for (int j = 0; j < NI; ++j) {
    const int t1 = 2 * j + 1, t2 = 2 * j + 2, t3 = 2 * j + 3;
    const bool s2 = t2 < NT, s3 = t3 < NT;
    // p0: db0 ks0 mh0
    RDB8(0, 0); RDA8(0, 0, 0);
    STA8(1, 1, t1);
    SYNCA; MM168(0); ENDP; BAR2;
    // p1: db0 ks0 mh1
    RDA8(0, 0, 1);
    STB8(1, 1, t1);
    SYNCA; MM168(1); ENDP; BAR2;
    // p2: db0 ks1 mh0
    RDB8(0, 1); RDA8(0, 1, 0);
    if (s2) STA8(0, 0, t2);
    SYNCA; MM168(0); ENDP; BAR2;
    // p3: db0 ks1 mh1  (+ wait: db1 = tile t1 fully resident)
    RDA8(0, 1, 1);
    if (s2) STB8(0, 0, t2);
    SYNCA; MM168(1); ENDP;
    if (j + 1 == NI) asm volatile("s_waitcnt vmcnt(0)" ::: "memory");
    else             asm volatile("s_waitcnt vmcnt(4)" ::: "memory");
    BAR2;
    // p4: db1 ks0 mh0
    RDB8(1, 0); RDA8(1, 0, 0);
    if (s2) STA8(0, 1, t2);
    SYNCA; MM168(0); ENDP; BAR2;
    // p5: db1 ks0 mh1
    RDA8(1, 0, 1);
    if (s2) STB8(0, 1, t2);
    SYNCA; MM168(1); ENDP; BAR2;
    // p6: db1 ks1 mh0
    RDB8(1, 1); RDA8(1, 1, 0);
    if (s3) STA8(1, 0, t3);
    SYNCA; MM168(0); ENDP; BAR2;
    // p7: db1 ks1 mh1  (+ wait: db0 = tile t2 fully resident)
    RDA8(1, 1, 1);
    if (s3) STB8(1, 0, t3);
    SYNCA; MM168(1); ENDP;
    asm volatile("s_waitcnt vmcnt(4)" ::: "memory");
    BAR2;
  }
#undef STA8
#undef STB8
#undef RDA8
#undef RDB8
#undef MM168
#undef SYNCA
#undef ENDP
#undef BAR2

#pragma unroll
  for (int m = 0; m < 8; m++) {
    size_t row = bm + wm * 128 + m * 16 + 4 * g;
#pragma unroll
    for (int n = 0; n < 4; n++) {
      size_t col = bn + wn * 64 + n * 16 + lq;
#pragma unroll
      for (int r = 0; r < 4; r++) {
        size_t idx = (row + r) * (size_t)N + col;
        if constexpr (MODE == 0) {
          ((u16*)Cout)[idx] = f2bf(acc[m][n][r]);
        } else if constexpr (MODE == 1) {
          ((float*)Cout)[idx] = ((const float*)Extra)[idx] + acc[m][n][r];
        } else {
          float a = bf2f(((const u16*)Extra)[idx]);
          float sil = a / (1.f + exp2f(-1.4426950408889634f * a));
          ((u16*)Cout)[idx] = f2bf(sil * acc[m][n][r]);
        }
      }
    }
  }
}

// ----------------- causal flash attention (LDS-staged) --------------
// grid (T/64, B*H); 4 waves/block; block owns 64 q-rows of one (b,h);
// wave w owns rows q0blk + 16w .. +16.  KV tile = 64.
// Q/K read from fused QKV buffer (row stride QS).
__global__ __launch_bounds__(256, 3) void attn_kernel(const u16* __restrict__ QKV,
                                                      const u16* __restrict__ VT,
                                                      u16* __restrict__ CTX) {
  __shared__ u16 Ks[64 * 128];    // 16 KB
  __shared__ u16 Vs[128 * 64];    // 16 KB
  __shared__ u16 P_all[4][16 * 72];  // 9 KB, per-wave padded P tile
  const int t = threadIdx.x;
  const int w = t >> 6, l = t & 63, g = l >> 4, lq = l & 15;
  u16* P = P_all[w];
  const int q0blk = blockIdx.x * 64;
  const int q0w = q0blk + w * 16;
  const int bh = blockIdx.y, b = bh >> 4, h = bh & 15;
  const u16* qp = QKV + (size_t)b * T_SEQ * QS + h * D_HEAD;
  const u16* kp = QKV + (size_t)b * T_SEQ * QS + E_DIM + h * D_HEAD;
  const u16* vp = VT + ((size_t)b * E_DIM + h * D_HEAD) * T_SEQ;

  short8 qf[4];
#pragma unroll
  for (int ks = 0; ks < 4; ks++)
    qf[ks] = *(const short8*)(qp + (size_t)(q0w + lq) * QS + ks * 32 + g * 8);

  f32x4 acc[8] = {};
  float m2[4], ls[4];
#pragma unroll
  for (int r = 0; r < 4; r++) { m2[r] = -1e30f; ls[r] = 0.f; }
  const float sc = 0.08838834764831845f * 1.4426950408889634f;  // 1/sqrt(128)*log2e

  const int kRow0 = 16 * w + (l >> 4);
  const int kChunk = l & 15;
  const int vRow0 = 32 * w + (l >> 3);
  const int vChunk = l & 7;

  for (int kv0 = 0; kv0 <= q0blk; kv0 += 64) {
#pragma unroll
    for (int j = 0; j < 4; j++) {
      int R = kRow0 + 4 * j;
      async16(Ks + (16 * w + 4 * j) * 128,
              kp + (size_t)(kv0 + R) * QS + ((kChunk ^ (R & 7)) << 3));
    }
#pragma unroll
    for (int j = 0; j < 4; j++) {
      int D = vRow0 + 8 * j;
      async16(Vs + (32 * w + 8 * j) * 64,
              vp + (size_t)D * T_SEQ + kv0 + ((vChunk ^ (D & 7)) << 3));
    }
    __syncthreads();

    f32x4 s[4];
#pragma unroll
    for (int ct = 0; ct < 4; ct++) {
      s[ct] = f32x4{0.f, 0.f, 0.f, 0.f};
#pragma unroll
      for (int ks = 0; ks < 4; ks++) {
        short8 kf = *(const short8*)(Ks + (ct * 16 + lq) * 128 +
                                     (((ks * 4 + g) ^ (lq & 7)) << 3));
        s[ct] = __builtin_amdgcn_mfma_f32_16x16x32_bf16(qf[ks], kf, s[ct], 0, 0, 0);
      }
    }
    float sv[4][4];
#pragma unroll
    for (int ct = 0; ct < 4; ct++)
#pragma unroll
      for (int r = 0; r < 4; r++) sv[ct][r] = s[ct][r] * sc;
    if (kv0 + 64 > q0w) {
#pragma unroll
      for (int ct = 0; ct < 4; ct++)
#pragma unroll
        for (int r = 0; r < 4; r++)
          if (kv0 + ct * 16 + lq > q0w + 4 * g + r) sv[ct][r] = -1e30f;
    }
    float mx[4];
#pragma unroll
    for (int r = 0; r < 4; r++)
      mx[r] = fmaxf(fmaxf(sv[0][r], sv[1][r]), fmaxf(sv[2][r], sv[3][r]));
#pragma unroll
    for (int off = 1; off < 16; off <<= 1)
#pragma unroll
      for (int r = 0; r < 4; r++) mx[r] = fmaxf(mx[r], __shfl_xor(mx[r], off));
#pragma unroll
    for (int r = 0; r < 4; r++) {
      float mn = fmaxf(m2[r], mx[r]);
      float sca = exp2f(m2[r] - mn);
      m2[r] = mn;
      float sum = 0.f;
#pragma unroll
      for (int ct = 0; ct < 4; ct++) {
        float pv = exp2f(sv[ct][r] - mn);
        sum += pv;
        P[(4 * g + r) * 72 + ct * 16 + lq] = f2bf(pv);
      }
      ls[r] = ls[r] * sca + sum;
#pragma unroll
      for (int n = 0; n < 8; n++) acc[n][r] *= sca;
    }
    short8 pa[2];
#pragma unroll
    for (int ks2 = 0; ks2 < 2; ks2++)
      pa[ks2] = *(const short8*)(P + lq * 72 + ks2 * 32 + g * 8);
#pragma unroll
    for (int n = 0; n < 8; n++)
#pragma unroll
      for (int ks2 = 0; ks2 < 2; ks2++) {
        short8 vf = *(const short8*)(Vs + (n * 16 + lq) * 64 +
                                     (((ks2 * 4 + g) ^ (lq & 7)) << 3));
        acc[n] = __builtin_amdgcn_mfma_f32_16x16x32_bf16(pa[ks2], vf, acc[n], 0, 0, 0);
      }
    __syncthreads();
  }

#pragma unroll
  for (int off = 1; off < 16; off <<= 1)
#pragma unroll
    for (int r = 0; r < 4; r++) ls[r] += __shfl_xor(ls[r], off);
  float inv[4];
#pragma unroll
  for (int r = 0; r < 4; r++) inv[r] = 1.f / ls[r];
  u16* cp = CTX + ((size_t)b * T_SEQ + q0w) * E_DIM + h * D_HEAD;
#pragma unroll
  for (int n = 0; n < 8; n++)
#pragma unroll
    for (int r = 0; r < 4; r++)
      cp[(size_t)(4 * g + r) * E_DIM + n * 16 + lq] = f2bf(acc[n][r] * inv[r]);
}

extern "C" void kernel_launch(void* const* d_in, const int* in_sizes, int n_in,
                              void* d_out, int out_size, void* d_ws, size_t ws_size,
                              hipStream_t stream) {
  (void)in_sizes; (void)n_in; (void)out_size; (void)ws_size;
  const float* x  = (const float*)d_in[0];
  const float* g1 = (const float*)d_in[1];
  const float* b1 = (const float*)d_in[2];
  const float* wq = (const float*)d_in[3];
  const float* wk = (const float*)d_in[4];
  const float* wv = (const float*)d_in[5];
  const float* wo = (const float*)d_in[6];
  const float* g2 = (const float*)d_in[7];
  const float* b2 = (const float*)d_in[8];
  const float* w1 = (const float*)d_in[9];
  const float* w2 = (const float*)d_in[10];
  const float* w3 = (const float*)d_in[11];
  float* out = (float*)d_out;

  const size_t EE2 = (size_t)E_DIM * E_DIM * 2;
  const size_t EF2 = (size_t)E_DIM * FFN_DIM * 2;
  const size_t ME2 = (size_t)M_ROWS * E_DIM * 2;
  char* p = (char*)d_ws;
  u16* wqkvT = (u16*)p; p += 3 * EE2;  // [3E][E] fused, rows 0..2047=wq^T
  u16* woT = (u16*)p; p += EE2;
  u16* w1T = (u16*)p; p += EF2;
  u16* w2T = (u16*)p; p += EF2;
  u16* w3T = (u16*)p; p += EF2;
  u16* Hb  = (u16*)p; p += ME2;
  u16* QKVb = (u16*)p; p += (size_t)M_ROWS * QS * 2;  // [4096][6144]
  u16* VTb = (u16*)p; p += ME2;
  u16* CTXb = (u16*)p; p += ME2;
  u16* U1b = QKVb;  // u1/gated (67MB) reuses QKVb+VTb (exactly 67MB)

  dim3 blk32(32, 8);
  // weights -> bf16 transposed [N][K]
  cvt_t_kernel<<<dim3(E_DIM / 32, E_DIM / 32), blk32, 0, stream>>>(wq, wqkvT, E_DIM, E_DIM);
  cvt_t_kernel<<<dim3(E_DIM / 32, E_DIM / 32), blk32, 0, stream>>>(wk, wqkvT + E_DIM * E_DIM, E_DIM, E_DIM);
  cvt_t_kernel<<<dim3(E_DIM / 32, E_DIM / 32), blk32, 0, stream>>>(wv, wqkvT + 2 * E_DIM * E_DIM, E_DIM, E_DIM);
  cvt_t_kernel<<<dim3(E_DIM / 32, E_DIM / 32), blk32, 0, stream>>>(wo, woT, E_DIM, E_DIM);
  cvt_t_kernel<<<dim3(FFN_DIM / 32, E_DIM / 32), blk32, 0, stream>>>(w1, w1T, E_DIM, FFN_DIM);
  cvt_t_kernel<<<dim3(FFN_DIM / 32, E_DIM / 32), blk32, 0, stream>>>(w2, w2T, E_DIM, FFN_DIM);
  cvt_t_kernel<<<dim3(E_DIM / 32, FFN_DIM / 32), blk32, 0, stream>>>(w3, w3T, FFN_DIM, E_DIM);

  // attention block
  ln_kernel<<<M_ROWS, 256, 0, stream>>>(x, g1, b1, Hb);
  // fused QKV GEMM: [4096][2048] x [6144][2048]^T -> [4096][6144]
  gemm8p<0><<<dim3(QS / 256, M_ROWS / 256), 512, 0, stream>>>(Hb, wqkvT, QKVb, nullptr, QS, E_DIM, 1);
  transpose_v_kernel<<<dim3(T_SEQ / 32, E_DIM / 32, 2), blk32, 0, stream>>>(QKVb, VTb);
  attn_kernel<<<dim3(T_SEQ / 64, 2 * N_HEAD), 256, 0, stream>>>(QKVb, VTb, CTXb);
  gemm8p<1><<<dim3(E_DIM / 256, M_ROWS / 256), 512, 0, stream>>>(CTXb, woT, out, x, E_DIM, E_DIM, 0);

  // SwiGLU MLP block
  ln_kernel<<<M_ROWS, 256, 0, stream>>>(out, g2, b2, Hb);
  gemm8p<0><<<dim3(FFN_DIM / 256, M_ROWS / 256), 512, 0, stream>>>(Hb, w1T, U1b, nullptr, FFN_DIM, E_DIM, 1);
  gemm8p<2><<<dim3(FFN_DIM / 256, M_ROWS / 256), 512, 0, stream>>>(Hb, w2T, U1b, U1b, FFN_DIM, E_DIM, 1);
  gemm8p<1><<<dim3(E_DIM / 256, M_ROWS / 256), 512, 0, stream>>>(U1b, w3T, out, out, E_DIM, FFN_DIM, 0);
}

// Round 6
// 957.238 us; speedup vs baseline: 1.3406x; 1.0669x over previous
//
#include <hip/hip_runtime.h>

// Transformer layer, bf16 MFMA compute, fp32 I/O.
// B=2 T=2048 E=2048 H=16 DH=128 FFN=8192. Needs ~235MB workspace.

#define T_SEQ 2048
#define E_DIM 2048
#define N_HEAD 16
#define D_HEAD 128
#define FFN_DIM 8192
#define M_ROWS 4096  // B*T
#define QS (3 * E_DIM)  // fused QKV row stride

typedef unsigned short u16;
typedef short short8 __attribute__((ext_vector_type(8)));
typedef float f32x4 __attribute__((ext_vector_type(4)));

#define DEV __device__ __forceinline__

DEV u16 f2bf(float f) {
  unsigned u = __float_as_uint(f);
  u += 0x7fffu + ((u >> 16) & 1u);
  return (u16)(u >> 16);
}
DEV float bf2f(u16 h) { return __uint_as_float(((unsigned)h) << 16); }

DEV void async16(void* lds, const void* g) {
  __builtin_amdgcn_global_load_lds((const __attribute__((address_space(1))) void*)g,
                                   (__attribute__((address_space(3))) void*)lds, 16, 0, 0);
}

// ---------------- LayerNorm: fp32 [rows][E] -> bf16 -----------------
__global__ __launch_bounds__(256) void ln_kernel(const float* __restrict__ x,
                                                 const float* __restrict__ gw,
                                                 const float* __restrict__ bw,
                                                 u16* __restrict__ out) {
  int row = blockIdx.x;
  int t = threadIdx.x;
  const float4* xr = (const float4*)(x + (size_t)row * E_DIM);
  float4 a = xr[t], c = xr[t + 256];
  float s = a.x + a.y + a.z + a.w + c.x + c.y + c.z + c.w;
  float q = a.x * a.x + a.y * a.y + a.z * a.z + a.w * a.w +
            c.x * c.x + c.y * c.y + c.z * c.z + c.w * c.w;
  for (int off = 32; off > 0; off >>= 1) {
    s += __shfl_down(s, off);
    q += __shfl_down(q, off);
  }
  __shared__ float red[8];
  if ((t & 63) == 0) { red[(t >> 6) * 2] = s; red[(t >> 6) * 2 + 1] = q; }
  __syncthreads();
  s = red[0] + red[2] + red[4] + red[6];
  q = red[1] + red[3] + red[5] + red[7];
  float mu = s * (1.f / E_DIM);
  float rs = rsqrtf(q * (1.f / E_DIM) - mu * mu + 1e-5f);
  const float4* g4 = (const float4*)gw;
  const float4* b4 = (const float4*)bw;
  float4 g0 = g4[t], g1v = g4[t + 256], e0 = b4[t], e1 = b4[t + 256];
  ushort4 o0, o1;
  o0.x = f2bf((a.x - mu) * rs * g0.x + e0.x);
  o0.y = f2bf((a.y - mu) * rs * g0.y + e0.y);
  o0.z = f2bf((a.z - mu) * rs * g0.z + e0.z);
  o0.w = f2bf((a.w - mu) * rs * g0.w + e0.w);
  o1.x = f2bf((c.x - mu) * rs * g1v.x + e1.x);
  o1.y = f2bf((c.y - mu) * rs * g1v.y + e1.y);
  o1.z = f2bf((c.z - mu) * rs * g1v.z + e1.z);
  o1.w = f2bf((c.w - mu) * rs * g1v.w + e1.w);
  ((ushort4*)(out + (size_t)row * E_DIM))[t] = o0;
  ((ushort4*)(out + (size_t)row * E_DIM))[t + 256] = o1;
}

// ------- convert+transpose: fp32 W[K][N] -> bf16 WT[N][K] -----------
__global__ __launch_bounds__(256) void cvt_t_kernel(const float* __restrict__ W,
                                                    u16* __restrict__ WT,
                                                    int Kd, int Nd) {
  __shared__ float tile[32][33];
  int tx = threadIdx.x, ty = threadIdx.y;
  int n0 = blockIdx.x * 32, k0 = blockIdx.y * 32;
#pragma unroll
  for (int i = 0; i < 4; i++)
    tile[ty + i * 8][tx] = W[(size_t)(k0 + ty + i * 8) * Nd + n0 + tx];
  __syncthreads();
#pragma unroll
  for (int i = 0; i < 4; i++)
    WT[(size_t)(n0 + ty + i * 8) * Kd + k0 + tx] = f2bf(tile[tx][ty + i * 8]);
}

// -- transpose V from fused QKV: bf16 [B*T][QS] col 4096+ -> [B][E][T]
__global__ __launch_bounds__(256) void transpose_v_kernel(const u16* __restrict__ qkv,
                                                          u16* __restrict__ vt) {
  __shared__ u16 tile[32][33];
  int tx = threadIdx.x, ty = threadIdx.y;
  int b = blockIdx.z;
  int t0 = blockIdx.x * 32, e0 = blockIdx.y * 32;
#pragma unroll
  for (int i = 0; i < 4; i++)
    tile[ty + i * 8][tx] =
        qkv[(size_t)(b * T_SEQ + t0 + ty + i * 8) * QS + 2 * E_DIM + e0 + tx];
  __syncthreads();
#pragma unroll
  for (int i = 0; i < 4; i++)
    vt[((size_t)b * E_DIM + e0 + ty + i * 8) * T_SEQ + t0 + tx] = tile[tx][ty + i * 8];
}

// ======= GEMM BM_x256xBK64, 8-phase schedule, paired-row LDS ========
// C[M][N] = A[M][K] * BT[N][K]^T.  512 thr = 8 waves (2M x 4N).
// BM_=256: wave owns 128x64, 16 MFMA/phase, LDS 128KB.
// BM_=128: wave owns  64x64,  8 MFMA/phase, LDS  96KB (full chip for
//          N=2048 shapes: grid 8x32=256).
// LDS units [2 dbuf][2 KS-half][BM_ rows][32 cols] but with PAIRED-ROW
// physical layout: 16B-chunk p holds (row=2*(p>>3)+(p&1),
// kchunk=((p&7)>>1)^((p>>3)&3)).  Bank word = (p&7)*4 mod 32 -> row
// term vanishes; each 8-lane read group covers all 8 bank blocks
// (round-2-proven zero-conflict pattern).
// Phase = {ds_read subtile + stage unit} -> barrier -> lgkmcnt(0) ->
// setprio(1) MFMA setprio(0) -> barrier.  Stagger (iter j, t1=2j+1,
// t2=2j+2, t3=2j+3): p0:A(1,1,t1) p1:B(1,1,t1) p2:A(0,0,t2)
// p3:B(0,0,t2)+vmcnt(VC) p4:A(0,1,t2) p5:B(0,1,t2) p6:A(1,0,t3)
// p7:B(1,0,t3)+vmcnt(VC).  Counted vmcnt never 0 except final drain.
// MODE 0: bf16 C.  MODE 1: Cout(f32)=Extra(f32)+acc.
// MODE 2: Cout(bf16)=silu(Extra bf16)*acc (Extra may alias Cout).
template <int MODE, int BM_>
__global__ __launch_bounds__(512, 1) void gemm8p(const u16* __restrict__ A,
                                                 const u16* __restrict__ BT,
                                                 void* __restrict__ Cout,
                                                 const void* __restrict__ Extra,
                                                 int N, int K, int colMajorXcd) {
  constexpr int MM = BM_ / 64;        // mm fragments per MH phase (4 or 2)
  constexpr int AUNIT = BM_ * 32;     // elements per (DB,KS) A unit
  constexpr int VC = (BM_ == 256) ? 4 : 3;  // counted vmcnt
  __shared__ u16 Abuf[4 * AUNIT];
  __shared__ u16 Bbuf[4 * 8192];
  const int t = threadIdx.x;
  const int w = t >> 6, l = t & 63, g = l >> 4, lq = l & 15;
  const int wm = w >> 2, wn = w & 3;

  // T1: bijective XCD swizzle (all grids have nwg % 8 == 0)
  const int gx = gridDim.x, gy = gridDim.y;
  const int nwg = gx * gy;
  int lin = colMajorXcd ? (blockIdx.x * gy + blockIdx.y)
                        : (blockIdx.y * gx + blockIdx.x);
  const int qq = nwg >> 3;
  int wg = (lin & 7) * qq + (lin >> 3);
  int bx, by;
  if (colMajorXcd) { bx = wg / gy; by = wg - bx * gy; }
  else             { by = wg / gx; bx = wg - by * gx; }
  const size_t bm = (size_t)by * BM_, bn = (size_t)bx * 256;

  // staging lane constants (paired-row): lane l covers
  // row = 2*(l>>3) + (l&1), kchunk = ((l>>1)&3) ^ ((l>>3)&3)
  const int srcrow = ((l >> 3) << 1) | (l & 1);
  const int csrc = ((((l >> 1) & 3) ^ ((l >> 3) & 3)) << 3);
  const u16* aSrc = A + (bm + w * 16 + srcrow) * (size_t)K + csrc;
  const u16* bSrc = BT + (bn + w * 16 + srcrow) * (size_t)K + csrc;
  // read lane constant: ch7 = (lq&1) + 2*(g ^ ((lq>>1)&3)), el offset
  const int rdoff = (((lq & 1) + 2 * (g ^ ((lq >> 1) & 3))) << 3);

#define STA8(DB, KS, TILE)                                                    \
  {                                                                           \
    u16* Ad = Abuf + (DB) * (2 * AUNIT) + (KS)*AUNIT + w * 512;               \
    const u16* as_ = aSrc + (size_t)(TILE)*64 + (KS)*32;                      \
    async16(Ad, as_);                                                         \
    if constexpr (BM_ == 256) async16(Ad + 4096, as_ + (size_t)128 * K);      \
  }
#define STB8(DB, KS, TILE)                                                    \
  {                                                                           \
    u16* Bd = Bbuf + (DB)*16384 + (KS)*8192 + w * 512;                        \
    const u16* bs_ = bSrc + (size_t)(TILE)*64 + (KS)*32;                      \
    async16(Bd, bs_);                                                         \
    async16(Bd + 4096, bs_ + (size_t)128 * K);                                \
  }
#define RDA8(DB, KS, MH)                                                      \
  _Pragma("unroll") for (int mm = 0; mm < MM; ++mm)                           \
      af[mm] = *(const short8*)(Abuf + (DB) * (2 * AUNIT) + (KS)*AUNIT +      \
                                (wm * (BM_ / 4) + (MH) * (BM_ / 8) + mm * 8 + \
                                 (lq >> 1)) * 64 + rdoff);
#define RDB8(DB, KS)                                                          \
  _Pragma("unroll") for (int nn = 0; nn < 4; ++nn)                            \
      bf[nn] = *(const short8*)(Bbuf + (DB)*16384 + (KS)*8192 +               \
                                (wn * 32 + nn * 8 + (lq >> 1)) * 64 + rdoff);
#define MM168(MH)                                                             \
  _Pragma("unroll") for (int mm = 0; mm < MM; ++mm)                           \
      _Pragma("unroll") for (int nn = 0; nn < 4; ++nn)                        \
          acc[(MH)*MM + mm][nn] = __builtin_amdgcn_mfma_f32_16x16x32_bf16(    \
              af[mm], bf[nn], acc[(MH)*MM + mm][nn], 0, 0, 0);
#define SYNCA                                                                 \
  asm volatile("s_barrier" ::: "memory");                                     \
  asm volatile("s_waitcnt lgkmcnt(0)" ::: "memory");                          \
  __builtin_amdgcn_sched_barrier(0);                                          \
  __builtin_amdgcn_s_setprio(1);
#define ENDP __builtin_amdgcn_s_setprio(0);
#define BAR2 asm volatile("s_barrier" ::: "memory");
#define WAITVC                                                                \
  if constexpr (BM_ == 256) asm volatile("s_waitcnt vmcnt(4)" ::: "memory");  \
  else                      asm volatile("s_waitcnt vmcnt(3)" ::: "memory");

  const int NT = K >> 6, NI = NT >> 1;
  f32x4 acc[2 * MM][4] = {};
  short8 af[MM > 4 ? MM : 4], bf[4];

  // prologue: tile0 both K-halves + tile1 K-half0
  STA8(0, 0, 0); STB8(0, 0, 0);
  STA8(0, 1, 0); STB8(0, 1, 0);
  STA8(1, 0, 1); STB8(1, 0, 1);
  WAITVC;  // tile0 resident, tile1-KS0 in flight
  BAR2;

  for (int j = 0; j < NI; ++j) {
    const int t1 = 2 * j + 1, t2 = 2 * j + 2, t3 = 2 * j + 3;
    const bool s2 = t2 < NT, s3 = t3 < NT;
    // p0: db0 ks0 mh0
    RDB8(0, 0); RDA8(0, 0, 0);
    STA8(1, 1, t1);
    SYNCA; MM168(0); ENDP; BAR2;
    // p1: db0 ks0 mh1
    RDA8(0, 0, 1);
    STB8(1, 1, t1);
    SYNCA; MM168(1); ENDP; BAR2;
    // p2: db0 ks1 mh0
    RDB8(0, 1); RDA8(0, 1, 0);
    if (s2) STA8(0, 0, t2);
    SYNCA; MM168(0); ENDP; BAR2;
    // p3: db0 ks1 mh1  (+ wait: db1 = tile t1 fully resident)
    RDA8(0, 1, 1);
    if (s2) STB8(0, 0, t2);
    SYNCA; MM168(1); ENDP;
    if (j + 1 == NI) { asm volatile("s_waitcnt vmcnt(0)" ::: "memory"); }
    else { WAITVC; }
    BAR2;
    // p4: db1 ks0 mh0
    RDB8(1, 0); RDA8(1, 0, 0);
    if (s2) STA8(0, 1, t2);
    SYNCA; MM168(0); ENDP; BAR2;
    // p5: db1 ks0 mh1
    RDA8(1, 0, 1);
    if (s2) STB8(0, 1, t2);
    SYNCA; MM168(1); ENDP; BAR2;
    // p6: db1 ks1 mh0
    RDB8(1, 1); RDA8(1, 1, 0);
    if (s3) STA8(1, 0, t3);
    SYNCA; MM168(0); ENDP; BAR2;
    // p7: db1 ks1 mh1  (+ wait: db0 = tile t2 fully resident)
    RDA8(1, 1, 1);
    if (s3) STB8(1, 0, t3);
    SYNCA; MM168(1); ENDP;
    WAITVC;
    BAR2;
  }
#undef STA8
#undef STB8
#undef RDA8
#undef RDB8
#undef MM168
#undef SYNCA
#undef ENDP
#undef BAR2
#undef WAITVC

#pragma unroll
  for (int m = 0; m < 2 * MM; m++) {
    size_t row = bm + wm * (BM_ / 2) + m * 16 + 4 * g;
#pragma unroll
    for (int n = 0; n < 4; n++) {
      size_t col = bn + wn * 64 + n * 16 + lq;
#pragma unroll
      for (int r = 0; r < 4; r++) {
        size_t idx = (row + r) * (size_t)N + col;
        if constexpr (MODE == 0) {
          ((u16*)Cout)[idx] = f2bf(acc[m][n][r]);
        } else if constexpr (MODE == 1) {
          ((float*)Cout)[idx] = ((const float*)Extra)[idx] + acc[m][n][r];
        } else {
          float a = bf2f(((const u16*)Extra)[idx]);
          float sil = a / (1.f + exp2f(-1.4426950408889634f * a));
          ((u16*)Cout)[idx] = f2bf(sil * acc[m][n][r]);
        }
      }
    }
  }
}

// ----------------- causal flash attention (LDS-staged) --------------
// grid (T/64, B*H); 4 waves/block; block owns 64 q-rows of one (b,h);
// wave w owns rows q0blk + 16w .. +16.  KV tile = 64.
// Q/K read from fused QKV buffer (row stride QS).
__global__ __launch_bounds__(256, 3) void attn_kernel(const u16* __restrict__ QKV,
                                                      const u16* __restrict__ VT,
                                                      u16* __restrict__ CTX) {
  __shared__ u16 Ks[64 * 128];    // 16 KB
  __shared__ u16 Vs[128 * 64];    // 16 KB
  __shared__ u16 P_all[4][16 * 72];  // 9 KB, per-wave padded P tile
  const int t = threadIdx.x;
  const int w = t >> 6, l = t & 63, g = l >> 4, lq = l & 15;
  u16* P = P_all[w];
  const int q0blk = blockIdx.x * 64;
  const int q0w = q0blk + w * 16;
  const int bh = blockIdx.y, b = bh >> 4, h = bh & 15;
  const u16* qp = QKV + (size_t)b * T_SEQ * QS + h * D_HEAD;
  const u16* kp = QKV + (size_t)b * T_SEQ * QS + E_DIM + h * D_HEAD;
  const u16* vp = VT + ((size_t)b * E_DIM + h * D_HEAD) * T_SEQ;

  short8 qf[4];
#pragma unroll
  for (int ks = 0; ks < 4; ks++)
    qf[ks] = *(const short8*)(qp + (size_t)(q0w + lq) * QS + ks * 32 + g * 8);

  f32x4 acc[8] = {};
  float m2[4], ls[4];
#pragma unroll
  for (int r = 0; r < 4; r++) { m2[r] = -1e30f; ls[r] = 0.f; }
  const float sc = 0.08838834764831845f * 1.4426950408889634f;  // 1/sqrt(128)*log2e

  const int kRow0 = 16 * w + (l >> 4);
  const int kChunk = l & 15;
  const int vRow0 = 32 * w + (l >> 3);
  const int vChunk = l & 7;

  for (int kv0 = 0; kv0 <= q0blk; kv0 += 64) {
#pragma unroll
    for (int j = 0; j < 4; j++) {
      int R = kRow0 + 4 * j;
      async16(Ks + (16 * w + 4 * j) * 128,
              kp + (size_t)(kv0 + R) * QS + ((kChunk ^ (R & 7)) << 3));
    }
#pragma unroll
    for (int j = 0; j < 4; j++) {
      int D = vRow0 + 8 * j;
      async16(Vs + (32 * w + 8 * j) * 64,
              vp + (size_t)D * T_SEQ + kv0 + ((vChunk ^ (D & 7)) << 3));
    }
    __syncthreads();

    f32x4 s[4];
#pragma unroll
    for (int ct = 0; ct < 4; ct++) {
      s[ct] = f32x4{0.f, 0.f, 0.f, 0.f};
#pragma unroll
      for (int ks = 0; ks < 4; ks++) {
        short8 kf = *(const short8*)(Ks + (ct * 16 + lq) * 128 +
                                     (((ks * 4 + g) ^ (lq & 7)) << 3));
        s[ct] = __builtin_amdgcn_mfma_f32_16x16x32_bf16(qf[ks], kf, s[ct], 0, 0, 0);
      }
    }
    float sv[4][4];
#pragma unroll
    for (int ct = 0; ct < 4; ct++)
#pragma unroll
      for (int r = 0; r < 4; r++) sv[ct][r] = s[ct][r] * sc;
    if (kv0 + 64 > q0w) {
#pragma unroll
      for (int ct = 0; ct < 4; ct++)
#pragma unroll
        for (int r = 0; r < 4; r++)
          if (kv0 + ct * 16 + lq > q0w + 4 * g + r) sv[ct][r] = -1e30f;
    }
    float mx[4];
#pragma unroll
    for (int r = 0; r < 4; r++)
      mx[r] = fmaxf(fmaxf(sv[0][r], sv[1][r]), fmaxf(sv[2][r], sv[3][r]));
#pragma unroll
    for (int off = 1; off < 16; off <<= 1)
#pragma unroll
      for (int r = 0; r < 4; r++) mx[r] = fmaxf(mx[r], __shfl_xor(mx[r], off));
#pragma unroll
    for (int r = 0; r < 4; r++) {
      float mn = fmaxf(m2[r], mx[r]);
      float sca = exp2f(m2[r] - mn);
      m2[r] = mn;
      float sum = 0.f;
#pragma unroll
      for (int ct = 0; ct < 4; ct++) {
        float pv = exp2f(sv[ct][r] - mn);
        sum += pv;
        P[(4 * g + r) * 72 + ct * 16 + lq] = f2bf(pv);
      }
      ls[r] = ls[r] * sca + sum;
#pragma unroll
      for (int n = 0; n < 8; n++) acc[n][r] *= sca;
    }
    short8 pa[2];
#pragma unroll
    for (int ks2 = 0; ks2 < 2; ks2++)
      pa[ks2] = *(const short8*)(P + lq * 72 + ks2 * 32 + g * 8);
#pragma unroll
    for (int n = 0; n < 8; n++)
#pragma unroll
      for (int ks2 = 0; ks2 < 2; ks2++) {
        short8 vf = *(const short8*)(Vs + (n * 16 + lq) * 64 +
                                     (((ks2 * 4 + g) ^ (lq & 7)) << 3));
        acc[n] = __builtin_amdgcn_mfma_f32_16x16x32_bf16(pa[ks2], vf, acc[n], 0, 0, 0);
      }
    __syncthreads();
  }

#pragma unroll
  for (int off = 1; off < 16; off <<= 1)
#pragma unroll
    for (int r = 0; r < 4; r++) ls[r] += __shfl_xor(ls[r], off);
  float inv[4];
#pragma unroll
  for (int r = 0; r < 4; r++) inv[r] = 1.f / ls[r];
  u16* cp = CTX + ((size_t)b * T_SEQ + q0w) * E_DIM + h * D_HEAD;
#pragma unroll
  for (int n = 0; n < 8; n++)
#pragma unroll
    for (int r = 0; r < 4; r++)
      cp[(size_t)(4 * g + r) * E_DIM + n * 16 + lq] = f2bf(acc[n][r] * inv[r]);
}

extern "C" void kernel_launch(void* const* d_in, const int* in_sizes, int n_in,
                              void* d_out, int out_size, void* d_ws, size_t ws_size,
                              hipStream_t stream) {
  (void)in_sizes; (void)n_in; (void)out_size; (void)ws_size;
  const float* x  = (const float*)d_in[0];
  const float* g1 = (const float*)d_in[1];
  const float* b1 = (const float*)d_in[2];
  const float* wq = (const float*)d_in[3];
  const float* wk = (const float*)d_in[4];
  const float* wv = (const float*)d_in[5];
  const float* wo = (const float*)d_in[6];
  const float* g2 = (const float*)d_in[7];
  const float* b2 = (const float*)d_in[8];
  const float* w1 = (const float*)d_in[9];
  const float* w2 = (const float*)d_in[10];
  const float* w3 = (const float*)d_in[11];
  float* out = (float*)d_out;

  const size_t EE2 = (size_t)E_DIM * E_DIM * 2;
  const size_t EF2 = (size_t)E_DIM * FFN_DIM * 2;
  const size_t ME2 = (size_t)M_ROWS * E_DIM * 2;
  char* p = (char*)d_ws;
  u16* wqkvT = (u16*)p; p += 3 * EE2;  // [3E][E] fused, rows 0..2047=wq^T
  u16* woT = (u16*)p; p += EE2;
  u16* w1T = (u16*)p; p += EF2;
  u16* w2T = (u16*)p; p += EF2;
  u16* w3T = (u16*)p; p += EF2;
  u16* Hb  = (u16*)p; p += ME2;
  u16* QKVb = (u16*)p; p += (size_t)M_ROWS * QS * 2;  // [4096][6144]
  u16* VTb = (u16*)p; p += ME2;
  u16* CTXb = (u16*)p; p += ME2;
  u16* U1b = QKVb;  // u1/gated (67MB) reuses QKVb+VTb

  dim3 blk32(32, 8);
  // weights -> bf16 transposed [N][K]
  cvt_t_kernel<<<dim3(E_DIM / 32, E_DIM / 32), blk32, 0, stream>>>(wq, wqkvT, E_DIM, E_DIM);
  cvt_t_kernel<<<dim3(E_DIM / 32, E_DIM / 32), blk32, 0, stream>>>(wk, wqkvT + E_DIM * E_DIM, E_DIM, E_DIM);
  cvt_t_kernel<<<dim3(E_DIM / 32, E_DIM / 32), blk32, 0, stream>>>(wv, wqkvT + 2 * E_DIM * E_DIM, E_DIM, E_DIM);
  cvt_t_kernel<<<dim3(E_DIM / 32, E_DIM / 32), blk32, 0, stream>>>(wo, woT, E_DIM, E_DIM);
  cvt_t_kernel<<<dim3(FFN_DIM / 32, E_DIM / 32), blk32, 0, stream>>>(w1, w1T, E_DIM, FFN_DIM);
  cvt_t_kernel<<<dim3(FFN_DIM / 32, E_DIM / 32), blk32, 0, stream>>>(w2, w2T, E_DIM, FFN_DIM);
  cvt_t_kernel<<<dim3(E_DIM / 32, FFN_DIM / 32), blk32, 0, stream>>>(w3, w3T, FFN_DIM, E_DIM);

  // attention block
  ln_kernel<<<M_ROWS, 256, 0, stream>>>(x, g1, b1, Hb);
  // fused QKV GEMM: [4096][2048] x [6144][2048]^T -> [4096][6144]
  gemm8p<0, 128><<<dim3(QS / 256, M_ROWS / 128), 512, 0, stream>>>(Hb, wqkvT, QKVb, nullptr, QS, E_DIM, 1);
  transpose_v_kernel<<<dim3(T_SEQ / 32, E_DIM / 32, 2), blk32, 0, stream>>>(QKVb, VTb);
  attn_kernel<<<dim3(T_SEQ / 64, 2 * N_HEAD), 256, 0, stream>>>(QKVb, VTb, CTXb);
  gemm8p<1, 128><<<dim3(E_DIM / 256, M_ROWS / 128), 512, 0, stream>>>(CTXb, woT, out, x, E_DIM, E_DIM, 1);

  // SwiGLU MLP block
  ln_kernel<<<M_ROWS, 256, 0, stream>>>(out, g2, b2, Hb);
  gemm8p<0, 256><<<dim3(FFN_DIM / 256, M_ROWS / 256), 512, 0, stream>>>(Hb, w1T, U1b, nullptr, FFN_DIM, E_DIM, 1);
  gemm8p<2, 256><<<dim3(FFN_DIM / 256, M_ROWS / 256), 512, 0, stream>>>(Hb, w2T, U1b, U1b, FFN_DIM, E_DIM, 1);
  gemm8p<1, 128><<<dim3(E_DIM / 256, M_ROWS / 128), 512, 0, stream>>>(U1b, w3T, out, out, E_DIM, FFN_DIM, 1);
}